// Round 6
// baseline (413.936 us; speedup 1.0000x reference)
//
#include <hip/hip_runtime.h>
#include <math.h>

#define NMODES 32
#define NPAIR 496

// T2 matrix in module-scope device memory (d_ws may be zero-sized).
__device__ float2 g_T2[NMODES * NMODES];

__device__ __forceinline__ void cfma(float2& acc, float2 a, float bre, float bim) {
    acc.x = fmaf(a.x, bre, fmaf(-a.y, bim, acc.x));
    acc.y = fmaf(a.x, bim, fmaf(a.y, bre, acc.y));
}

// ---------------------------------------------------------------------------
// Setup kernel: 1024 threads, one block. Builds T2 (32x32 complex).
//   U = expm(iH): scale (||X||<=1) + degree-11 Taylor via Paterson-Stockmeyer
//   (X2, X3, then 3 Horner matmuls) + s squarings. 1 barrier per matmul
//   (ping-pong buffers).
//   W = U^T U; mix = (1.1I - W)^{-1} W via pivot-free Gauss-Jordan
//   (leading blocks of 1.1I - W have sigma_min >= 0.1), ping-pong,
//   1 barrier per iteration.
//   T2[i][j] = -|kappa_i||kappa_j| * (0.5*delta_ij + mix[i][j])
// Thread map: i = tid>>5 (row), j = tid&31 (col); thread owns Aug cols j, j+32.
// ---------------------------------------------------------------------------
__global__ __launch_bounds__(1024) void setup_kernel(const float* __restrict__ params,
                                                     const float* __restrict__ kappa) {
    // 5120 float2 = 40 KB pool, manually partitioned & reused
    __shared__ float2 pool[5120];
    float2* Xb  = pool;          // 1024: scaled iH        (later Aug0 low)
    float2* X2b = pool + 1024;   // 1024: X^2              (later Aug0 high)
    float2* X3b = pool + 2048;   // 1024: X^3              (later Wbuf)
    float2* P0b = pool + 3072;   // 1024: Horner ping      (later Aug1 low)
    float2* P1b = pool + 4096;   // 1024: Horner pong      (later Aug1 high)
    float2* Aug0 = pool;         // 2048 (32 x 64)
    float2* Wbuf = pool + 2048;  // 1024
    float2* Aug1 = pool + 3072;  // 2048 (32 x 64)

    __shared__ int sh_s;
    __shared__ float sh_scale;

    const int tid = threadIdx.x;
    const int i = tid >> 5;
    const int j = tid & 31;
    const int ij = i * 32 + j;

    // --- build H (into Xb) ---
    {
        float2 h;
        if (i == j) {
            float d;
            if (i < 31) {
                d = params[2 * NPAIR + i];
            } else {
                d = 0.0f;
                for (int r = 0; r < 31; ++r) d -= params[2 * NPAIR + r];
            }
            h = make_float2(d, 0.0f);
        } else {
            int a = (i < j) ? i : j;
            int b = (i < j) ? j : i;
            int idx = 31 * a - (a * (a - 1)) / 2 + (b - a - 1);  // row-major triu
            float re = params[idx];
            float im = params[NPAIR + idx];
            h = (i < j) ? make_float2(re, im) : make_float2(re, -im);
        }
        Xb[ij] = h;
    }
    __syncthreads();

    // --- inf-norm (wave 0) -> scaling exponent, threshold 1.0 ---
    if (tid < 32) {
        float s = 0.0f;
        for (int c = 0; c < 32; ++c) {
            float2 v = Xb[tid * 32 + c];
            s += sqrtf(v.x * v.x + v.y * v.y);
        }
        for (int off = 16; off > 0; off >>= 1)
            s = fmaxf(s, __shfl_down(s, off));
        if (tid == 0) {
            int sc_n = 0;
            float sc = 1.0f;
            while (s > 1.0f && sc_n < 40) { s *= 0.5f; sc *= 0.5f; ++sc_n; }
            sh_s = sc_n;
            sh_scale = sc;
        }
    }
    __syncthreads();

    // --- X = (i*H) * 2^{-s} (in place, own element) ---
    {
        float sc = sh_scale;
        float2 v = Xb[ij];
        Xb[ij] = make_float2(-v.y * sc, v.x * sc);
    }
    __syncthreads();

    // --- X2 = X*X ---
    {
        float2 acc = {0, 0};
        for (int k = 0; k < 32; ++k) {
            float2 a = Xb[i * 32 + k];
            float2 b = Xb[k * 32 + j];
            cfma(acc, a, b.x, b.y);
        }
        X2b[ij] = acc;
    }
    __syncthreads();

    // --- X3 = X2*X ---
    {
        float2 acc = {0, 0};
        for (int k = 0; k < 32; ++k) {
            float2 a = X2b[i * 32 + k];
            float2 b = Xb[k * 32 + j];
            cfma(acc, a, b.x, b.y);
        }
        X3b[ij] = acc;
    }
    __syncthreads();

    // Taylor coefficients c_k = 1/k!
    const float c0 = 1.0f, c1 = 1.0f, c2 = 0.5f;
    const float c3 = 1.0f / 6.0f, c4 = 1.0f / 24.0f, c5 = 1.0f / 120.0f;
    const float c6 = 1.0f / 720.0f, c7 = 1.0f / 5040.0f, c8 = 1.0f / 40320.0f;
    const float c9 = 1.0f / 362880.0f, c10 = 1.0f / 3628800.0f, c11 = 1.0f / 39916800.0f;

    const float2 xv = Xb[ij];
    const float2 x2v = X2b[ij];
    const float del = (i == j) ? 1.0f : 0.0f;

    // --- P0 = B3 = c9 I + c10 X + c11 X2 ---
    P0b[ij] = make_float2(c9 * del + c10 * xv.x + c11 * x2v.x,
                          c10 * xv.y + c11 * x2v.y);
    __syncthreads();

    // --- 3 Horner steps: P <- B_m + X3*P, m = 2,1,0 ---
    float2* hp_cur = P0b;
    float2* hp_nxt = P1b;
    const float bm_d[3] = {c6, c3, c0};
    const float bm_x[3] = {c7, c4, c1};
    const float bm_x2[3] = {c8, c5, c2};
    for (int hm = 0; hm < 3; ++hm) {
        float2 acc = {0, 0};
        for (int k = 0; k < 32; ++k) {
            float2 a = X3b[i * 32 + k];
            float2 b = hp_cur[k * 32 + j];
            cfma(acc, a, b.x, b.y);
        }
        acc.x += bm_d[hm] * del + bm_x[hm] * xv.x + bm_x2[hm] * x2v.x;
        acc.y += bm_x[hm] * xv.y + bm_x2[hm] * x2v.y;
        hp_nxt[ij] = acc;
        __syncthreads();
        float2* t = hp_cur; hp_cur = hp_nxt; hp_nxt = t;
    }

    // --- squarings: cur <- cur*cur, s times ---
    {
        int s = sh_s;
        for (int q = 0; q < s; ++q) {
            float2 acc = {0, 0};
            for (int k = 0; k < 32; ++k) {
                float2 a = hp_cur[i * 32 + k];
                float2 b = hp_cur[k * 32 + j];
                cfma(acc, a, b.x, b.y);
            }
            hp_nxt[ij] = acc;
            __syncthreads();
            float2* t = hp_cur; hp_cur = hp_nxt; hp_nxt = t;
        }
    }

    // --- W = U^T U  (U = hp_cur) -> Wbuf ---
    {
        float2 acc = {0, 0};
        for (int k = 0; k < 32; ++k) {
            float2 a = hp_cur[k * 32 + i];
            float2 b = hp_cur[k * 32 + j];
            cfma(acc, a, b.x, b.y);
        }
        Wbuf[ij] = acc;
    }
    __syncthreads();

    // --- Aug0 = [1.1I - W | W]  (32 x 64, row stride 64) ---
    {
        float2 w = Wbuf[ij];
        Aug0[i * 64 + j] = make_float2(1.1f * del - w.x, -w.y);
        Aug0[i * 64 + j + 32] = w;
    }
    __syncthreads();

    // --- pivot-free Gauss-Jordan, ping-pong, 1 barrier/iter ---
    float2* gc = Aug0;
    float2* gn = Aug1;
    for (int p = 0; p < 32; ++p) {
        float2 d = gc[p * 64 + p];
        float2 f = gc[i * 64 + p];
        float2 rpL = gc[p * 64 + j];
        float2 rpR = gc[p * 64 + j + 32];
        float2 vL = gc[i * 64 + j];
        float2 vR = gc[i * 64 + j + 32];
        float den = 1.0f / (d.x * d.x + d.y * d.y);
        float2 pr = make_float2(d.x * den, -d.y * den);  // 1/d
        if (i == p) {
            gn[i * 64 + j] = make_float2(rpL.x * pr.x - rpL.y * pr.y,
                                         rpL.x * pr.y + rpL.y * pr.x);
            gn[i * 64 + j + 32] = make_float2(rpR.x * pr.x - rpR.y * pr.y,
                                              rpR.x * pr.y + rpR.y * pr.x);
        } else {
            float2 g = make_float2(f.x * pr.x - f.y * pr.y, f.x * pr.y + f.y * pr.x);
            vL.x -= g.x * rpL.x - g.y * rpL.y;
            vL.y -= g.x * rpL.y + g.y * rpL.x;
            vR.x -= g.x * rpR.x - g.y * rpR.y;
            vR.y -= g.x * rpR.y + g.y * rpR.x;
            gn[i * 64 + j] = vL;
            gn[i * 64 + j + 32] = vR;
        }
        __syncthreads();
        float2* t = gc; gc = gn; gn = t;
    }

    // --- T2 (mix = right half of gc) ---
    {
        float2 mix = gc[i * 64 + j + 32];
        float kk2 = fabsf(kappa[i]) * fabsf(kappa[j]);
        g_T2[ij] = make_float2(-kk2 * (((i == j) ? 0.5f : 0.0f) + mix.x),
                               -kk2 * mix.y);
    }
}

// ---------------------------------------------------------------------------
// Main ODE kernel, split-K x4: block = 128 threads = 2 waves = 1 batch.
// lane: m = tid>>2 (mode), h = tid&3 (K-quarter). Each lane holds a quarter
// of T2 row m (8 complex = 16 VGPRs), computes a quarter dot; combine via
// __shfl_xor 1 then 2 (within quad). 4096 waves -> 4 waves/SIMD.
// Stage vectors ping-pong between two padded LDS buffers (1 barrier/stage,
// WAR-free by construction). Quarter q of x stored at float offset q*20
// (80 B stride staggers banks). Output: real plane only.
// ---------------------------------------------------------------------------
__device__ __forceinline__ float2 f_eval(const float* __restrict__ xq,
                                         float2 ym,
                                         const float2* __restrict__ t2q,
                                         float om, float nl2) {
    float2 acc0 = make_float2(0.0f, 0.0f);
    float2 acc1 = make_float2(0.0f, 0.0f);
#pragma unroll
    for (int q = 0; q < 4; ++q) {
        float4 v = *reinterpret_cast<const float4*>(xq + 4 * q);  // x[h*8+2q], x[h*8+2q+1]
        float2 ta = t2q[2 * q];
        float2 tb = t2q[2 * q + 1];
        acc0.x = fmaf(ta.x, v.x, acc0.x);
        acc0.x = fmaf(-ta.y, v.y, acc0.x);
        acc0.y = fmaf(ta.x, v.y, acc0.y);
        acc0.y = fmaf(ta.y, v.x, acc0.y);
        acc1.x = fmaf(tb.x, v.z, acc1.x);
        acc1.x = fmaf(-tb.y, v.w, acc1.x);
        acc1.y = fmaf(tb.x, v.w, acc1.y);
        acc1.y = fmaf(tb.y, v.z, acc1.y);
    }
    float2 acc = make_float2(acc0.x + acc1.x, acc0.y + acc1.y);
    acc.x += __shfl_xor(acc.x, 1);
    acc.y += __shfl_xor(acc.y, 1);
    acc.x += __shfl_xor(acc.x, 2);
    acc.y += __shfl_xor(acc.y, 2);
    float w = fmaf(nl2, fmaf(ym.x, ym.x, ym.y * ym.y), om);
    return make_float2(acc.x - w * ym.y, acc.y + w * ym.x);
}

__global__ __launch_bounds__(128) void ode_kernel(const float* __restrict__ A0r,
                                                  const float* __restrict__ A0i,
                                                  const float* __restrict__ omega,
                                                  const float* __restrict__ nln,
                                                  float* __restrict__ out,
                                                  long long out_size) {
    const int tid = threadIdx.x;
    const int m = tid >> 2;   // 0..31
    const int h = tid & 3;    // 0..3
    const int b = blockIdx.x;

    // quarter T2 row: 8 complex = 16 VGPRs
    float2 t2q[8];
#pragma unroll
    for (int k = 0; k < 8; ++k) t2q[k] = g_T2[m * NMODES + h * 8 + k];

    const float om = omega[m];
    const float nl = nln[0];
    const float nl2 = nl * nl;
    const float dt = 1.0f / 199.0f;
    const float hdt = 0.5f * dt;
    const float sdt = dt / 6.0f;

    float2 a;
    if (m < 24) a = make_float2(A0r[b * 24 + m], A0i[b * 24 + m]);
    else        a = make_float2(1.0f, 0.0f);

    // ping-pong buffers, quarter q at float offset q*20 (16 payload + 4 pad)
    __shared__ __align__(16) float buf0[80];
    __shared__ __align__(16) float buf1[80];
    const int wslot = (m >> 3) * 20 + (m & 7) * 2;  // float offset of x[m]
    const float* rq0 = buf0 + h * 20;
    const float* rq1 = buf1 + h * 20;

    // t = 0: output + stage buffer
    if (h == 0) {
        long long o = (long long)b * 32 + m;
        if (o < out_size) out[o] = a.x;
        *reinterpret_cast<float2*>(buf0 + wslot) = a;
    }
    __syncthreads();

    for (int t = 1; t < 200; ++t) {
        float2 k1 = f_eval(rq0, a, t2q, om, nl2);
        float2 y2 = make_float2(fmaf(hdt, k1.x, a.x), fmaf(hdt, k1.y, a.y));
        if (h == 0) *reinterpret_cast<float2*>(buf1 + wslot) = y2;
        __syncthreads();

        float2 k2 = f_eval(rq1, y2, t2q, om, nl2);
        float2 y3 = make_float2(fmaf(hdt, k2.x, a.x), fmaf(hdt, k2.y, a.y));
        if (h == 0) *reinterpret_cast<float2*>(buf0 + wslot) = y3;
        __syncthreads();

        float2 k3 = f_eval(rq0, y3, t2q, om, nl2);
        float2 y4 = make_float2(fmaf(dt, k3.x, a.x), fmaf(dt, k3.y, a.y));
        if (h == 0) *reinterpret_cast<float2*>(buf1 + wslot) = y4;
        __syncthreads();

        float2 k4 = f_eval(rq1, y4, t2q, om, nl2);

        a.x = fmaf(sdt, k1.x + 2.0f * k2.x + 2.0f * k3.x + k4.x, a.x);
        a.y = fmaf(sdt, k1.y + 2.0f * k2.y + 2.0f * k3.y + k4.y, a.y);

        if (h == 0) {
            *reinterpret_cast<float2*>(buf0 + wslot) = a;
            long long o = (long long)t * 65536 + (long long)b * 32 + m;
            if (o < out_size) out[o] = a.x;
        }
        __syncthreads();
    }
}

extern "C" void kernel_launch(void* const* d_in, const int* in_sizes, int n_in,
                              void* d_out, int out_size, void* d_ws, size_t ws_size,
                              hipStream_t stream) {
    const float* A0r = (const float*)d_in[0];
    const float* A0i = (const float*)d_in[1];
    const float* omega = (const float*)d_in[2];
    const float* kappa = (const float*)d_in[3];
    const float* nln = (const float*)d_in[4];
    const float* params = (const float*)d_in[5];

    setup_kernel<<<1, 1024, 0, stream>>>(params, kappa);
    ode_kernel<<<2048, 128, 0, stream>>>(A0r, A0i, omega, nln,
                                         (float*)d_out, (long long)out_size);
}

// Round 7
// 397.022 us; speedup vs baseline: 1.0426x; 1.0426x over previous
//
#include <hip/hip_runtime.h>
#include <math.h>

#define NMODES 32
#define NPAIR 496

// T2 matrix in module-scope device memory (d_ws may be zero-sized).
__device__ float2 g_T2[NMODES * NMODES];

__device__ __forceinline__ void cfma(float2& acc, float2 a, float bre, float bim) {
    acc.x = fmaf(a.x, bre, fmaf(-a.y, bim, acc.x));
    acc.y = fmaf(a.x, bim, fmaf(a.y, bre, acc.y));
}

// ---------------------------------------------------------------------------
// Setup kernel (unchanged from round 6): 1024 threads, one block.
//   U = expm(iH) via scale + degree-11 Paterson-Stockmeyer Taylor + squarings.
//   W = U^T U; mix = (1.1I - W)^{-1} W via pivot-free Gauss-Jordan.
//   T2[i][j] = -|kappa_i||kappa_j| * (0.5*delta_ij + mix[i][j])
// ---------------------------------------------------------------------------
__global__ __launch_bounds__(1024) void setup_kernel(const float* __restrict__ params,
                                                     const float* __restrict__ kappa) {
    __shared__ float2 pool[5120];
    float2* Xb  = pool;
    float2* X2b = pool + 1024;
    float2* X3b = pool + 2048;
    float2* P0b = pool + 3072;
    float2* P1b = pool + 4096;
    float2* Aug0 = pool;
    float2* Wbuf = pool + 2048;
    float2* Aug1 = pool + 3072;

    __shared__ int sh_s;
    __shared__ float sh_scale;

    const int tid = threadIdx.x;
    const int i = tid >> 5;
    const int j = tid & 31;
    const int ij = i * 32 + j;

    {
        float2 h;
        if (i == j) {
            float d;
            if (i < 31) {
                d = params[2 * NPAIR + i];
            } else {
                d = 0.0f;
                for (int r = 0; r < 31; ++r) d -= params[2 * NPAIR + r];
            }
            h = make_float2(d, 0.0f);
        } else {
            int a = (i < j) ? i : j;
            int b = (i < j) ? j : i;
            int idx = 31 * a - (a * (a - 1)) / 2 + (b - a - 1);
            float re = params[idx];
            float im = params[NPAIR + idx];
            h = (i < j) ? make_float2(re, im) : make_float2(re, -im);
        }
        Xb[ij] = h;
    }
    __syncthreads();

    if (tid < 32) {
        float s = 0.0f;
        for (int c = 0; c < 32; ++c) {
            float2 v = Xb[tid * 32 + c];
            s += sqrtf(v.x * v.x + v.y * v.y);
        }
        for (int off = 16; off > 0; off >>= 1)
            s = fmaxf(s, __shfl_down(s, off));
        if (tid == 0) {
            int sc_n = 0;
            float sc = 1.0f;
            while (s > 1.0f && sc_n < 40) { s *= 0.5f; sc *= 0.5f; ++sc_n; }
            sh_s = sc_n;
            sh_scale = sc;
        }
    }
    __syncthreads();

    {
        float sc = sh_scale;
        float2 v = Xb[ij];
        Xb[ij] = make_float2(-v.y * sc, v.x * sc);
    }
    __syncthreads();

    {
        float2 acc = {0, 0};
        for (int k = 0; k < 32; ++k) {
            float2 a = Xb[i * 32 + k];
            float2 b = Xb[k * 32 + j];
            cfma(acc, a, b.x, b.y);
        }
        X2b[ij] = acc;
    }
    __syncthreads();

    {
        float2 acc = {0, 0};
        for (int k = 0; k < 32; ++k) {
            float2 a = X2b[i * 32 + k];
            float2 b = Xb[k * 32 + j];
            cfma(acc, a, b.x, b.y);
        }
        X3b[ij] = acc;
    }
    __syncthreads();

    const float c0 = 1.0f, c1 = 1.0f, c2 = 0.5f;
    const float c3 = 1.0f / 6.0f, c4 = 1.0f / 24.0f, c5 = 1.0f / 120.0f;
    const float c6 = 1.0f / 720.0f, c7 = 1.0f / 5040.0f, c8 = 1.0f / 40320.0f;
    const float c9 = 1.0f / 362880.0f, c10 = 1.0f / 3628800.0f, c11 = 1.0f / 39916800.0f;

    const float2 xv = Xb[ij];
    const float2 x2v = X2b[ij];
    const float del = (i == j) ? 1.0f : 0.0f;

    P0b[ij] = make_float2(c9 * del + c10 * xv.x + c11 * x2v.x,
                          c10 * xv.y + c11 * x2v.y);
    __syncthreads();

    float2* hp_cur = P0b;
    float2* hp_nxt = P1b;
    const float bm_d[3] = {c6, c3, c0};
    const float bm_x[3] = {c7, c4, c1};
    const float bm_x2[3] = {c8, c5, c2};
    for (int hm = 0; hm < 3; ++hm) {
        float2 acc = {0, 0};
        for (int k = 0; k < 32; ++k) {
            float2 a = X3b[i * 32 + k];
            float2 b = hp_cur[k * 32 + j];
            cfma(acc, a, b.x, b.y);
        }
        acc.x += bm_d[hm] * del + bm_x[hm] * xv.x + bm_x2[hm] * x2v.x;
        acc.y += bm_x[hm] * xv.y + bm_x2[hm] * x2v.y;
        hp_nxt[ij] = acc;
        __syncthreads();
        float2* t = hp_cur; hp_cur = hp_nxt; hp_nxt = t;
    }

    {
        int s = sh_s;
        for (int q = 0; q < s; ++q) {
            float2 acc = {0, 0};
            for (int k = 0; k < 32; ++k) {
                float2 a = hp_cur[i * 32 + k];
                float2 b = hp_cur[k * 32 + j];
                cfma(acc, a, b.x, b.y);
            }
            hp_nxt[ij] = acc;
            __syncthreads();
            float2* t = hp_cur; hp_cur = hp_nxt; hp_nxt = t;
        }
    }

    {
        float2 acc = {0, 0};
        for (int k = 0; k < 32; ++k) {
            float2 a = hp_cur[k * 32 + i];
            float2 b = hp_cur[k * 32 + j];
            cfma(acc, a, b.x, b.y);
        }
        Wbuf[ij] = acc;
    }
    __syncthreads();

    {
        float2 w = Wbuf[ij];
        Aug0[i * 64 + j] = make_float2(1.1f * del - w.x, -w.y);
        Aug0[i * 64 + j + 32] = w;
    }
    __syncthreads();

    float2* gc = Aug0;
    float2* gn = Aug1;
    for (int p = 0; p < 32; ++p) {
        float2 d = gc[p * 64 + p];
        float2 f = gc[i * 64 + p];
        float2 rpL = gc[p * 64 + j];
        float2 rpR = gc[p * 64 + j + 32];
        float2 vL = gc[i * 64 + j];
        float2 vR = gc[i * 64 + j + 32];
        float den = 1.0f / (d.x * d.x + d.y * d.y);
        float2 pr = make_float2(d.x * den, -d.y * den);
        if (i == p) {
            gn[i * 64 + j] = make_float2(rpL.x * pr.x - rpL.y * pr.y,
                                         rpL.x * pr.y + rpL.y * pr.x);
            gn[i * 64 + j + 32] = make_float2(rpR.x * pr.x - rpR.y * pr.y,
                                              rpR.x * pr.y + rpR.y * pr.x);
        } else {
            float2 g = make_float2(f.x * pr.x - f.y * pr.y, f.x * pr.y + f.y * pr.x);
            vL.x -= g.x * rpL.x - g.y * rpL.y;
            vL.y -= g.x * rpL.y + g.y * rpL.x;
            vR.x -= g.x * rpR.x - g.y * rpR.y;
            vR.y -= g.x * rpR.y + g.y * rpR.x;
            gn[i * 64 + j] = vL;
            gn[i * 64 + j + 32] = vR;
        }
        __syncthreads();
        float2* t = gc; gc = gn; gn = t;
    }

    {
        float2 mix = gc[i * 64 + j + 32];
        float kk2 = fabsf(kappa[i]) * fabsf(kappa[j]);
        g_T2[ij] = make_float2(-kk2 * (((i == j) ? 0.5f : 0.0f) + mix.x),
                               -kk2 * mix.y);
    }
}

// ---------------------------------------------------------------------------
// Main ODE kernel: DPP-systolic matvec. Block = 64 threads = 1 wave = 1 batch.
// Lane l holds real-expanded state x[l]: l<32 -> Re a_l, l>=32 -> Im a_{l-32}.
// 64x64 real matvec y' = Ttilde * x done entirely on the VALU:
//   3 shfl_xor (16/32/48) give each lane 4 row-variant copies; then 4 chains
//   of 16 v_fmac_f32 with DPP row_ror:k sweep all 64 columns. T-row is stored
//   per-lane PERMUTED so coefficient (q,k) matches the rotated operand:
//   t[q*16+k] = Ttilde[l][16*(r^q) + ((c-k)&15)], r=l>>4, c=l&15.
//   (row_ror:N => lane i reads lane (i-N)&15 within its row of 16.)
// Nonlinear term: x2 = shfl_xor(x,32) is the re<->im partner; w = om+nl2*|A|^2;
// contribution sgn*w*x2 (sgn = -1 for re-lanes, +1 for im-lanes).
// Zero LDS, zero barriers, 3 DS instr/stage -> off the LDS-pipe bottleneck.
// ---------------------------------------------------------------------------
#define FMROR(acc, xv, tv, K)                                                   \
    asm("v_fmac_f32 %0, %1, %2 row_ror:" #K " row_mask:0xf bank_mask:0xf"       \
        : "+v"(acc) : "v"(xv), "v"(tv))

#define K_STEP(K)                                                               \
    FMROR(a0, x,  t[K],      K);                                                \
    FMROR(a1, x1, t[16 + K], K);                                                \
    FMROR(a2, x2, t[32 + K], K);                                                \
    FMROR(a3, x3, t[48 + K], K)

__device__ __forceinline__ float f_ev(float x, const float* __restrict__ t,
                                      float om, float nl2, float sgn) {
    float x1 = __shfl_xor(x, 16);
    float x2 = __shfl_xor(x, 32);
    float x3 = __shfl_xor(x, 48);
    float a0 = 0.0f, a1 = 0.0f, a2 = 0.0f, a3 = 0.0f;
    a0 = fmaf(x, t[0], a0);
    a1 = fmaf(x1, t[16], a1);
    a2 = fmaf(x2, t[32], a2);
    a3 = fmaf(x3, t[48], a3);
    K_STEP(1);  K_STEP(2);  K_STEP(3);  K_STEP(4);  K_STEP(5);
    K_STEP(6);  K_STEP(7);  K_STEP(8);  K_STEP(9);  K_STEP(10);
    K_STEP(11); K_STEP(12); K_STEP(13); K_STEP(14); K_STEP(15);
    float w = fmaf(nl2, fmaf(x, x, x2 * x2), om);
    return (a0 + a1) + (a2 + a3) + sgn * w * x2;
}

__global__ __launch_bounds__(64) void ode_kernel(const float* __restrict__ A0r,
                                                 const float* __restrict__ A0i,
                                                 const float* __restrict__ omega,
                                                 const float* __restrict__ nln,
                                                 float* __restrict__ out,
                                                 long long out_size) {
    const int lane = threadIdx.x;
    const int m = lane & 31;       // mode
    const int part = lane >> 5;    // 0 = Re, 1 = Im
    const int r = lane >> 4;       // row-of-16 (0..3)
    const int c = lane & 15;       // col within row
    const int b = blockIdx.x;

    // Per-lane permuted Ttilde row: t[q*16+k] = Ttilde[l][16*(r^q)+((c-k)&15)]
    float t[64];
#pragma unroll
    for (int q = 0; q < 4; ++q) {
#pragma unroll
        for (int k = 0; k < 16; ++k) {
            int j = 16 * (r ^ q) + ((c - k) & 15);
            int jm = j & 31;
            int jp = j >> 5;
            float2 tv = g_T2[m * NMODES + jm];
            float val;
            if (part == 0) val = (jp == 0) ? tv.x : -tv.y;
            else           val = (jp == 0) ? tv.y : tv.x;
            t[q * 16 + k] = val;
        }
    }

    const float om = omega[m];
    const float nl = nln[0];
    const float nl2 = nl * nl;
    const float sgn = part ? 1.0f : -1.0f;
    const float dt = 1.0f / 199.0f;
    const float hdt = 0.5f * dt;
    const float sdt = dt / 6.0f;

    float x;
    if (part == 0) x = (m < 24) ? A0r[b * 24 + m] : 1.0f;
    else           x = (m < 24) ? A0i[b * 24 + m] : 0.0f;

    // t = 0 output (real plane only, guarded)
    if (part == 0) {
        long long o = (long long)b * 32 + m;
        if (o < out_size) out[o] = x;
    }

    for (int st = 1; st < 200; ++st) {
        float k1 = f_ev(x, t, om, nl2, sgn);
        float y  = fmaf(hdt, k1, x);
        float k2 = f_ev(y, t, om, nl2, sgn);
        y = fmaf(hdt, k2, x);
        float k3 = f_ev(y, t, om, nl2, sgn);
        y = fmaf(dt, k3, x);
        float k4 = f_ev(y, t, om, nl2, sgn);

        x = fmaf(sdt, k1 + 2.0f * k2 + 2.0f * k3 + k4, x);

        if (part == 0) {
            long long o = (long long)st * 65536 + (long long)b * 32 + m;
            if (o < out_size) out[o] = x;
        }
    }
}

extern "C" void kernel_launch(void* const* d_in, const int* in_sizes, int n_in,
                              void* d_out, int out_size, void* d_ws, size_t ws_size,
                              hipStream_t stream) {
    const float* A0r = (const float*)d_in[0];
    const float* A0i = (const float*)d_in[1];
    const float* omega = (const float*)d_in[2];
    const float* kappa = (const float*)d_in[3];
    const float* nln = (const float*)d_in[4];
    const float* params = (const float*)d_in[5];

    setup_kernel<<<1, 1024, 0, stream>>>(params, kappa);
    ode_kernel<<<2048, 64, 0, stream>>>(A0r, A0i, omega, nln,
                                        (float*)d_out, (long long)out_size);
}

// Round 8
// 396.886 us; speedup vs baseline: 1.0430x; 1.0003x over previous
//
#include <hip/hip_runtime.h>
#include <math.h>

#define NMODES 32
#define NPAIR 496

// T2 matrix in module-scope device memory (d_ws may be zero-sized).
__device__ float2 g_T2[NMODES * NMODES];

__device__ __forceinline__ void cfma(float2& acc, float2 a, float bre, float bim) {
    acc.x = fmaf(a.x, bre, fmaf(-a.y, bim, acc.x));
    acc.y = fmaf(a.x, bim, fmaf(a.y, bre, acc.y));
}

// ---------------------------------------------------------------------------
// Setup kernel (unchanged): 1024 threads, one block.
//   U = expm(iH) via scale + degree-11 Paterson-Stockmeyer Taylor + squarings.
//   W = U^T U; mix = (1.1I - W)^{-1} W via pivot-free Gauss-Jordan.
//   T2[i][j] = -|kappa_i||kappa_j| * (0.5*delta_ij + mix[i][j])
// ---------------------------------------------------------------------------
__global__ __launch_bounds__(1024) void setup_kernel(const float* __restrict__ params,
                                                     const float* __restrict__ kappa) {
    __shared__ float2 pool[5120];
    float2* Xb  = pool;
    float2* X2b = pool + 1024;
    float2* X3b = pool + 2048;
    float2* P0b = pool + 3072;
    float2* P1b = pool + 4096;
    float2* Aug0 = pool;
    float2* Wbuf = pool + 2048;
    float2* Aug1 = pool + 3072;

    __shared__ int sh_s;
    __shared__ float sh_scale;

    const int tid = threadIdx.x;
    const int i = tid >> 5;
    const int j = tid & 31;
    const int ij = i * 32 + j;

    {
        float2 h;
        if (i == j) {
            float d;
            if (i < 31) {
                d = params[2 * NPAIR + i];
            } else {
                d = 0.0f;
                for (int r = 0; r < 31; ++r) d -= params[2 * NPAIR + r];
            }
            h = make_float2(d, 0.0f);
        } else {
            int a = (i < j) ? i : j;
            int b = (i < j) ? j : i;
            int idx = 31 * a - (a * (a - 1)) / 2 + (b - a - 1);
            float re = params[idx];
            float im = params[NPAIR + idx];
            h = (i < j) ? make_float2(re, im) : make_float2(re, -im);
        }
        Xb[ij] = h;
    }
    __syncthreads();

    if (tid < 32) {
        float s = 0.0f;
        for (int c = 0; c < 32; ++c) {
            float2 v = Xb[tid * 32 + c];
            s += sqrtf(v.x * v.x + v.y * v.y);
        }
        for (int off = 16; off > 0; off >>= 1)
            s = fmaxf(s, __shfl_down(s, off));
        if (tid == 0) {
            int sc_n = 0;
            float sc = 1.0f;
            while (s > 1.0f && sc_n < 40) { s *= 0.5f; sc *= 0.5f; ++sc_n; }
            sh_s = sc_n;
            sh_scale = sc;
        }
    }
    __syncthreads();

    {
        float sc = sh_scale;
        float2 v = Xb[ij];
        Xb[ij] = make_float2(-v.y * sc, v.x * sc);
    }
    __syncthreads();

    {
        float2 acc = {0, 0};
        for (int k = 0; k < 32; ++k) {
            float2 a = Xb[i * 32 + k];
            float2 b = Xb[k * 32 + j];
            cfma(acc, a, b.x, b.y);
        }
        X2b[ij] = acc;
    }
    __syncthreads();

    {
        float2 acc = {0, 0};
        for (int k = 0; k < 32; ++k) {
            float2 a = X2b[i * 32 + k];
            float2 b = Xb[k * 32 + j];
            cfma(acc, a, b.x, b.y);
        }
        X3b[ij] = acc;
    }
    __syncthreads();

    const float c0 = 1.0f, c1 = 1.0f, c2 = 0.5f;
    const float c3 = 1.0f / 6.0f, c4 = 1.0f / 24.0f, c5 = 1.0f / 120.0f;
    const float c6 = 1.0f / 720.0f, c7 = 1.0f / 5040.0f, c8 = 1.0f / 40320.0f;
    const float c9 = 1.0f / 362880.0f, c10 = 1.0f / 3628800.0f, c11 = 1.0f / 39916800.0f;

    const float2 xv = Xb[ij];
    const float2 x2v = X2b[ij];
    const float del = (i == j) ? 1.0f : 0.0f;

    P0b[ij] = make_float2(c9 * del + c10 * xv.x + c11 * x2v.x,
                          c10 * xv.y + c11 * x2v.y);
    __syncthreads();

    float2* hp_cur = P0b;
    float2* hp_nxt = P1b;
    const float bm_d[3] = {c6, c3, c0};
    const float bm_x[3] = {c7, c4, c1};
    const float bm_x2[3] = {c8, c5, c2};
    for (int hm = 0; hm < 3; ++hm) {
        float2 acc = {0, 0};
        for (int k = 0; k < 32; ++k) {
            float2 a = X3b[i * 32 + k];
            float2 b = hp_cur[k * 32 + j];
            cfma(acc, a, b.x, b.y);
        }
        acc.x += bm_d[hm] * del + bm_x[hm] * xv.x + bm_x2[hm] * x2v.x;
        acc.y += bm_x[hm] * xv.y + bm_x2[hm] * x2v.y;
        hp_nxt[ij] = acc;
        __syncthreads();
        float2* t = hp_cur; hp_cur = hp_nxt; hp_nxt = t;
    }

    {
        int s = sh_s;
        for (int q = 0; q < s; ++q) {
            float2 acc = {0, 0};
            for (int k = 0; k < 32; ++k) {
                float2 a = hp_cur[i * 32 + k];
                float2 b = hp_cur[k * 32 + j];
                cfma(acc, a, b.x, b.y);
            }
            hp_nxt[ij] = acc;
            __syncthreads();
            float2* t = hp_cur; hp_cur = hp_nxt; hp_nxt = t;
        }
    }

    {
        float2 acc = {0, 0};
        for (int k = 0; k < 32; ++k) {
            float2 a = hp_cur[k * 32 + i];
            float2 b = hp_cur[k * 32 + j];
            cfma(acc, a, b.x, b.y);
        }
        Wbuf[ij] = acc;
    }
    __syncthreads();

    {
        float2 w = Wbuf[ij];
        Aug0[i * 64 + j] = make_float2(1.1f * del - w.x, -w.y);
        Aug0[i * 64 + j + 32] = w;
    }
    __syncthreads();

    float2* gc = Aug0;
    float2* gn = Aug1;
    for (int p = 0; p < 32; ++p) {
        float2 d = gc[p * 64 + p];
        float2 f = gc[i * 64 + p];
        float2 rpL = gc[p * 64 + j];
        float2 rpR = gc[p * 64 + j + 32];
        float2 vL = gc[i * 64 + j];
        float2 vR = gc[i * 64 + j + 32];
        float den = 1.0f / (d.x * d.x + d.y * d.y);
        float2 pr = make_float2(d.x * den, -d.y * den);
        if (i == p) {
            gn[i * 64 + j] = make_float2(rpL.x * pr.x - rpL.y * pr.y,
                                         rpL.x * pr.y + rpL.y * pr.x);
            gn[i * 64 + j + 32] = make_float2(rpR.x * pr.x - rpR.y * pr.y,
                                              rpR.x * pr.y + rpR.y * pr.x);
        } else {
            float2 g = make_float2(f.x * pr.x - f.y * pr.y, f.x * pr.y + f.y * pr.x);
            vL.x -= g.x * rpL.x - g.y * rpL.y;
            vL.y -= g.x * rpL.y + g.y * rpL.x;
            vR.x -= g.x * rpR.x - g.y * rpR.y;
            vR.y -= g.x * rpR.y + g.y * rpR.x;
            gn[i * 64 + j] = vL;
            gn[i * 64 + j + 32] = vR;
        }
        __syncthreads();
        float2* t = gc; gc = gn; gn = t;
    }

    {
        float2 mix = gc[i * 64 + j + 32];
        float kk2 = fabsf(kappa[i]) * fabsf(kappa[j]);
        g_T2[ij] = make_float2(-kk2 * (((i == j) ? 0.5f : 0.0f) + mix.x),
                               -kk2 * mix.y);
    }
}

// ---------------------------------------------------------------------------
// Main ODE kernel: DPP-systolic matvec. Block = 64 threads = 1 wave = 1 batch.
// Lane l holds real-expanded state x[l]: l<32 -> Re a_l, l>=32 -> Im a_{l-32}.
// 64x64 real matvec via 3 shfl_xor + 4 chains of 16 v_fmac_f32 row_ror:k.
// t[q*16+k] = Ttilde[l][16*(r^q) + ((c-k)&15)], r=l>>4, c=l&15.
//
// __launch_bounds__(64, 2): the grid (2048 waves) fixes occupancy at
// 2 waves/SIMD, so give the register allocator the matching 256-VGPR budget.
// Round-7 evidence: without it VGPR_Count=48 < sizeof(t)=64 -> t[] was
// spilled/rematerialized, costing ~60% of cycles in stalls.
// ---------------------------------------------------------------------------
#define FMROR(acc, xv, tv, K)                                                   \
    asm("v_fmac_f32 %0, %1, %2 row_ror:" #K " row_mask:0xf bank_mask:0xf"       \
        : "+v"(acc) : "v"(xv), "v"(tv))

#define K_STEP(K)                                                               \
    FMROR(a0, x,  t[K],      K);                                                \
    FMROR(a1, x1, t[16 + K], K);                                                \
    FMROR(a2, x2, t[32 + K], K);                                                \
    FMROR(a3, x3, t[48 + K], K)

__device__ __forceinline__ float f_ev(float x, const float* __restrict__ t,
                                      float om, float nl2, float sgn) {
    float x1 = __shfl_xor(x, 16);
    float x2 = __shfl_xor(x, 32);
    float x3 = __shfl_xor(x, 48);
    float a0 = 0.0f, a1 = 0.0f, a2 = 0.0f, a3 = 0.0f;
    a0 = fmaf(x, t[0], a0);
    a1 = fmaf(x1, t[16], a1);
    a2 = fmaf(x2, t[32], a2);
    a3 = fmaf(x3, t[48], a3);
    K_STEP(1);  K_STEP(2);  K_STEP(3);  K_STEP(4);  K_STEP(5);
    K_STEP(6);  K_STEP(7);  K_STEP(8);  K_STEP(9);  K_STEP(10);
    K_STEP(11); K_STEP(12); K_STEP(13); K_STEP(14); K_STEP(15);
    float w = fmaf(nl2, fmaf(x, x, x2 * x2), om);
    return (a0 + a1) + (a2 + a3) + sgn * w * x2;
}

__global__ __launch_bounds__(64, 2) void ode_kernel(const float* __restrict__ A0r,
                                                    const float* __restrict__ A0i,
                                                    const float* __restrict__ omega,
                                                    const float* __restrict__ nln,
                                                    float* __restrict__ out,
                                                    long long out_size) {
    const int lane = threadIdx.x;
    const int m = lane & 31;       // mode
    const int part = lane >> 5;    // 0 = Re, 1 = Im
    const int r = lane >> 4;       // row-of-16 (0..3)
    const int c = lane & 15;       // col within row
    const int b = blockIdx.x;

    // Per-lane permuted Ttilde row: t[q*16+k] = Ttilde[l][16*(r^q)+((c-k)&15)]
    float t[64];
#pragma unroll
    for (int q = 0; q < 4; ++q) {
#pragma unroll
        for (int k = 0; k < 16; ++k) {
            int j = 16 * (r ^ q) + ((c - k) & 15);
            int jm = j & 31;
            int jp = j >> 5;
            float2 tv = g_T2[m * NMODES + jm];
            float val;
            if (part == 0) val = (jp == 0) ? tv.x : -tv.y;
            else           val = (jp == 0) ? tv.y : tv.x;
            t[q * 16 + k] = val;
        }
    }

    const float om = omega[m];
    const float nl = nln[0];
    const float nl2 = nl * nl;
    const float sgn = part ? 1.0f : -1.0f;
    const float dt = 1.0f / 199.0f;
    const float hdt = 0.5f * dt;
    const float sdt = dt / 6.0f;

    float x;
    if (part == 0) x = (m < 24) ? A0r[b * 24 + m] : 1.0f;
    else           x = (m < 24) ? A0i[b * 24 + m] : 0.0f;

    // t = 0 output (real plane only, guarded)
    if (part == 0) {
        long long o = (long long)b * 32 + m;
        if (o < out_size) out[o] = x;
    }

    for (int st = 1; st < 200; ++st) {
        float k1 = f_ev(x, t, om, nl2, sgn);
        float y  = fmaf(hdt, k1, x);
        float k2 = f_ev(y, t, om, nl2, sgn);
        y = fmaf(hdt, k2, x);
        float k3 = f_ev(y, t, om, nl2, sgn);
        y = fmaf(dt, k3, x);
        float k4 = f_ev(y, t, om, nl2, sgn);

        x = fmaf(sdt, k1 + 2.0f * k2 + 2.0f * k3 + k4, x);

        if (part == 0) {
            long long o = (long long)st * 65536 + (long long)b * 32 + m;
            if (o < out_size) out[o] = x;
        }
    }
}

extern "C" void kernel_launch(void* const* d_in, const int* in_sizes, int n_in,
                              void* d_out, int out_size, void* d_ws, size_t ws_size,
                              hipStream_t stream) {
    const float* A0r = (const float*)d_in[0];
    const float* A0i = (const float*)d_in[1];
    const float* omega = (const float*)d_in[2];
    const float* kappa = (const float*)d_in[3];
    const float* nln = (const float*)d_in[4];
    const float* params = (const float*)d_in[5];

    setup_kernel<<<1, 1024, 0, stream>>>(params, kappa);
    ode_kernel<<<2048, 64, 0, stream>>>(A0r, A0i, omega, nln,
                                        (float*)d_out, (long long)out_size);
}

// Round 9
// 394.358 us; speedup vs baseline: 1.0496x; 1.0064x over previous
//
#include <hip/hip_runtime.h>
#include <math.h>

#define NMODES 32
#define NPAIR 496

// T2 matrix in module-scope device memory (d_ws may be zero-sized).
__device__ float2 g_T2[NMODES * NMODES];

__device__ __forceinline__ void cfma(float2& acc, float2 a, float bre, float bim) {
    acc.x = fmaf(a.x, bre, fmaf(-a.y, bim, acc.x));
    acc.y = fmaf(a.x, bim, fmaf(a.y, bre, acc.y));
}

// ---------------------------------------------------------------------------
// Setup kernel (unchanged): 1024 threads, one block.
//   U = expm(iH) via scale + degree-11 Paterson-Stockmeyer Taylor + squarings.
//   W = U^T U; mix = (1.1I - W)^{-1} W via pivot-free Gauss-Jordan.
//   T2[i][j] = -|kappa_i||kappa_j| * (0.5*delta_ij + mix[i][j])
// ---------------------------------------------------------------------------
__global__ __launch_bounds__(1024) void setup_kernel(const float* __restrict__ params,
                                                     const float* __restrict__ kappa) {
    __shared__ float2 pool[5120];
    float2* Xb  = pool;
    float2* X2b = pool + 1024;
    float2* X3b = pool + 2048;
    float2* P0b = pool + 3072;
    float2* P1b = pool + 4096;
    float2* Aug0 = pool;
    float2* Wbuf = pool + 2048;
    float2* Aug1 = pool + 3072;

    __shared__ int sh_s;
    __shared__ float sh_scale;

    const int tid = threadIdx.x;
    const int i = tid >> 5;
    const int j = tid & 31;
    const int ij = i * 32 + j;

    {
        float2 h;
        if (i == j) {
            float d;
            if (i < 31) {
                d = params[2 * NPAIR + i];
            } else {
                d = 0.0f;
                for (int r = 0; r < 31; ++r) d -= params[2 * NPAIR + r];
            }
            h = make_float2(d, 0.0f);
        } else {
            int a = (i < j) ? i : j;
            int b = (i < j) ? j : i;
            int idx = 31 * a - (a * (a - 1)) / 2 + (b - a - 1);
            float re = params[idx];
            float im = params[NPAIR + idx];
            h = (i < j) ? make_float2(re, im) : make_float2(re, -im);
        }
        Xb[ij] = h;
    }
    __syncthreads();

    if (tid < 32) {
        float s = 0.0f;
        for (int c = 0; c < 32; ++c) {
            float2 v = Xb[tid * 32 + c];
            s += sqrtf(v.x * v.x + v.y * v.y);
        }
        for (int off = 16; off > 0; off >>= 1)
            s = fmaxf(s, __shfl_down(s, off));
        if (tid == 0) {
            int sc_n = 0;
            float sc = 1.0f;
            while (s > 1.0f && sc_n < 40) { s *= 0.5f; sc *= 0.5f; ++sc_n; }
            sh_s = sc_n;
            sh_scale = sc;
        }
    }
    __syncthreads();

    {
        float sc = sh_scale;
        float2 v = Xb[ij];
        Xb[ij] = make_float2(-v.y * sc, v.x * sc);
    }
    __syncthreads();

    {
        float2 acc = {0, 0};
        for (int k = 0; k < 32; ++k) {
            float2 a = Xb[i * 32 + k];
            float2 b = Xb[k * 32 + j];
            cfma(acc, a, b.x, b.y);
        }
        X2b[ij] = acc;
    }
    __syncthreads();

    {
        float2 acc = {0, 0};
        for (int k = 0; k < 32; ++k) {
            float2 a = X2b[i * 32 + k];
            float2 b = Xb[k * 32 + j];
            cfma(acc, a, b.x, b.y);
        }
        X3b[ij] = acc;
    }
    __syncthreads();

    const float c0 = 1.0f, c1 = 1.0f, c2 = 0.5f;
    const float c3 = 1.0f / 6.0f, c4 = 1.0f / 24.0f, c5 = 1.0f / 120.0f;
    const float c6 = 1.0f / 720.0f, c7 = 1.0f / 5040.0f, c8 = 1.0f / 40320.0f;
    const float c9 = 1.0f / 362880.0f, c10 = 1.0f / 3628800.0f, c11 = 1.0f / 39916800.0f;

    const float2 xv = Xb[ij];
    const float2 x2v = X2b[ij];
    const float del = (i == j) ? 1.0f : 0.0f;

    P0b[ij] = make_float2(c9 * del + c10 * xv.x + c11 * x2v.x,
                          c10 * xv.y + c11 * x2v.y);
    __syncthreads();

    float2* hp_cur = P0b;
    float2* hp_nxt = P1b;
    const float bm_d[3] = {c6, c3, c0};
    const float bm_x[3] = {c7, c4, c1};
    const float bm_x2[3] = {c8, c5, c2};
    for (int hm = 0; hm < 3; ++hm) {
        float2 acc = {0, 0};
        for (int k = 0; k < 32; ++k) {
            float2 a = X3b[i * 32 + k];
            float2 b = hp_cur[k * 32 + j];
            cfma(acc, a, b.x, b.y);
        }
        acc.x += bm_d[hm] * del + bm_x[hm] * xv.x + bm_x2[hm] * x2v.x;
        acc.y += bm_x[hm] * xv.y + bm_x2[hm] * x2v.y;
        hp_nxt[ij] = acc;
        __syncthreads();
        float2* t = hp_cur; hp_cur = hp_nxt; hp_nxt = t;
    }

    {
        int s = sh_s;
        for (int q = 0; q < s; ++q) {
            float2 acc = {0, 0};
            for (int k = 0; k < 32; ++k) {
                float2 a = hp_cur[i * 32 + k];
                float2 b = hp_cur[k * 32 + j];
                cfma(acc, a, b.x, b.y);
            }
            hp_nxt[ij] = acc;
            __syncthreads();
            float2* t = hp_cur; hp_cur = hp_nxt; hp_nxt = t;
        }
    }

    {
        float2 acc = {0, 0};
        for (int k = 0; k < 32; ++k) {
            float2 a = hp_cur[k * 32 + i];
            float2 b = hp_cur[k * 32 + j];
            cfma(acc, a, b.x, b.y);
        }
        Wbuf[ij] = acc;
    }
    __syncthreads();

    {
        float2 w = Wbuf[ij];
        Aug0[i * 64 + j] = make_float2(1.1f * del - w.x, -w.y);
        Aug0[i * 64 + j + 32] = w;
    }
    __syncthreads();

    float2* gc = Aug0;
    float2* gn = Aug1;
    for (int p = 0; p < 32; ++p) {
        float2 d = gc[p * 64 + p];
        float2 f = gc[i * 64 + p];
        float2 rpL = gc[p * 64 + j];
        float2 rpR = gc[p * 64 + j + 32];
        float2 vL = gc[i * 64 + j];
        float2 vR = gc[i * 64 + j + 32];
        float den = 1.0f / (d.x * d.x + d.y * d.y);
        float2 pr = make_float2(d.x * den, -d.y * den);
        if (i == p) {
            gn[i * 64 + j] = make_float2(rpL.x * pr.x - rpL.y * pr.y,
                                         rpL.x * pr.y + rpL.y * pr.x);
            gn[i * 64 + j + 32] = make_float2(rpR.x * pr.x - rpR.y * pr.y,
                                              rpR.x * pr.y + rpR.y * pr.x);
        } else {
            float2 g = make_float2(f.x * pr.x - f.y * pr.y, f.x * pr.y + f.y * pr.x);
            vL.x -= g.x * rpL.x - g.y * rpL.y;
            vL.y -= g.x * rpL.y + g.y * rpL.x;
            vR.x -= g.x * rpR.x - g.y * rpR.y;
            vR.y -= g.x * rpR.y + g.y * rpR.x;
            gn[i * 64 + j] = vL;
            gn[i * 64 + j + 32] = vR;
        }
        __syncthreads();
        float2* t = gc; gc = gn; gn = t;
    }

    {
        float2 mix = gc[i * 64 + j + 32];
        float kk2 = fabsf(kappa[i]) * fabsf(kappa[j]);
        g_T2[ij] = make_float2(-kk2 * (((i == j) ? 0.5f : 0.0f) + mix.x),
                               -kk2 * mix.y);
    }
}

// ---------------------------------------------------------------------------
// Main ODE kernel: DPP-systolic matvec. Block = 64 threads = 1 wave = 1 batch.
// Lane l holds real-expanded state x[l]: l<32 -> Re a_l, l>=32 -> Im a_{l-32}.
// 64x64 real matvec via 3 shfl_xor + 4 chains of 16 v_fmac_f32 row_ror:k.
// t[q*16+k] = Ttilde[l][16*(r^q) + ((c-k)&15)], r=l>>4, c=l&15.
//
// ROUND-8 LESSON: f_ev as a *function taking float* t* defeated SROA -> t[]
// lived in scratch (VGPR_Count=48 < 64 needed), every fmac paid an L1 scratch
// load. Fix: F_EV is a MACRO expanded in kernel scope; t[] is only indexed
// with compile-time constants and its address never escapes -> promoted to
// 64 VGPRs under the __launch_bounds__(64,2) budget (grid fixes occupancy at
// 2 waves/SIMD anyway).
// ---------------------------------------------------------------------------
#define FMROR(acc, xv, tv, K)                                                   \
    asm("v_fmac_f32 %0, %1, %2 row_ror:" #K " row_mask:0xf bank_mask:0xf"       \
        : "+v"(acc) : "v"(xv), "v"(tv))

#define K_STEP(K)                                                               \
    FMROR(fa0, fx,  t[K],      K);                                              \
    FMROR(fa1, fx1, t[16 + K], K);                                              \
    FMROR(fa2, fx2, t[32 + K], K);                                              \
    FMROR(fa3, fx3, t[48 + K], K)

#define F_EV(RES, XIN)                                                          \
    {                                                                           \
        float fx = (XIN);                                                       \
        float fx1 = __shfl_xor(fx, 16);                                         \
        float fx2 = __shfl_xor(fx, 32);                                         \
        float fx3 = __shfl_xor(fx, 48);                                         \
        float fa0 = fx * t[0];                                                  \
        float fa1 = fx1 * t[16];                                                \
        float fa2 = fx2 * t[32];                                                \
        float fa3 = fx3 * t[48];                                                \
        K_STEP(1);  K_STEP(2);  K_STEP(3);  K_STEP(4);  K_STEP(5);              \
        K_STEP(6);  K_STEP(7);  K_STEP(8);  K_STEP(9);  K_STEP(10);             \
        K_STEP(11); K_STEP(12); K_STEP(13); K_STEP(14); K_STEP(15);             \
        float fw = fmaf(nl2, fmaf(fx, fx, fx2 * fx2), om);                      \
        RES = (fa0 + fa1) + (fa2 + fa3) + sgn * fw * fx2;                       \
    }

__global__ __launch_bounds__(64, 2) void ode_kernel(const float* __restrict__ A0r,
                                                    const float* __restrict__ A0i,
                                                    const float* __restrict__ omega,
                                                    const float* __restrict__ nln,
                                                    float* __restrict__ out,
                                                    long long out_size) {
    const int lane = threadIdx.x;
    const int m = lane & 31;       // mode
    const int part = lane >> 5;    // 0 = Re, 1 = Im
    const int r = lane >> 4;       // row-of-16 (0..3)
    const int c = lane & 15;       // col within row
    const int b = blockIdx.x;

    // Per-lane permuted Ttilde row: t[q*16+k] = Ttilde[l][16*(r^q)+((c-k)&15)]
    float t[64];
#pragma unroll
    for (int q = 0; q < 4; ++q) {
#pragma unroll
        for (int k = 0; k < 16; ++k) {
            int j = 16 * (r ^ q) + ((c - k) & 15);
            int jm = j & 31;
            int jp = j >> 5;
            float2 tv = g_T2[m * NMODES + jm];
            float val;
            if (part == 0) val = (jp == 0) ? tv.x : -tv.y;
            else           val = (jp == 0) ? tv.y : tv.x;
            t[q * 16 + k] = val;
        }
    }

    const float om = omega[m];
    const float nl = nln[0];
    const float nl2 = nl * nl;
    const float sgn = part ? 1.0f : -1.0f;
    const float dt = 1.0f / 199.0f;
    const float hdt = 0.5f * dt;
    const float sdt = dt / 6.0f;

    float x;
    if (part == 0) x = (m < 24) ? A0r[b * 24 + m] : 1.0f;
    else           x = (m < 24) ? A0i[b * 24 + m] : 0.0f;

    // t = 0 output (real plane only, guarded)
    if (part == 0) {
        long long o = (long long)b * 32 + m;
        if (o < out_size) out[o] = x;
    }

    for (int st = 1; st < 200; ++st) {
        float k1, k2, k3, k4;
        F_EV(k1, x);
        float y = fmaf(hdt, k1, x);
        F_EV(k2, y);
        y = fmaf(hdt, k2, x);
        F_EV(k3, y);
        y = fmaf(dt, k3, x);
        F_EV(k4, y);

        x = fmaf(sdt, k1 + 2.0f * k2 + 2.0f * k3 + k4, x);

        if (part == 0) {
            long long o = (long long)st * 65536 + (long long)b * 32 + m;
            if (o < out_size) out[o] = x;
        }
    }
}

extern "C" void kernel_launch(void* const* d_in, const int* in_sizes, int n_in,
                              void* d_out, int out_size, void* d_ws, size_t ws_size,
                              hipStream_t stream) {
    const float* A0r = (const float*)d_in[0];
    const float* A0i = (const float*)d_in[1];
    const float* omega = (const float*)d_in[2];
    const float* kappa = (const float*)d_in[3];
    const float* nln = (const float*)d_in[4];
    const float* params = (const float*)d_in[5];

    setup_kernel<<<1, 1024, 0, stream>>>(params, kappa);
    ode_kernel<<<2048, 64, 0, stream>>>(A0r, A0i, omega, nln,
                                        (float*)d_out, (long long)out_size);
}